// Round 1
// baseline (291.932 us; speedup 1.0000x reference)
//
#include <hip/hip_runtime.h>
#include <math.h>

#define Bn 16
#define Nn 256
#define Dd 64
#define Hh 64
#define Mm (Nn*(Nn-1)/2)   /* 32640 */
#define NT 8               /* 256/32 tiles per axis */

// ---------------------------------------------------------------------------
// Pair kernel: one block = one (batch, 32x32 pair tile). 256 threads.
// Each thread computes 4 pairs (same i, 4 consecutive j).
// h = relu(A[i,h] + C[j,h] + sum_d |Oi-Oj|_d * Wc[d,h] + (Oi*Oj)_d * Wd[d,h] + b1)
// Q = h @ W2 + b2
// ---------------------------------------------------------------------------
__global__ __launch_bounds__(256) void pair_kernel(
    const float* __restrict__ O,
    const float* __restrict__ W1,
    const float* __restrict__ b1,
    const float* __restrict__ W2,
    const float* __restrict__ b2,
    float* __restrict__ Q)
{
    __shared__ float s_oi[32][68];
    __shared__ float s_oj[32][68];
    __shared__ float s_A [32][68];   // includes +b1
    __shared__ float s_C [32][68];
    __shared__ float s_cw[64][32];   // |diff| weights, current 32-h half
    __shared__ float s_dw[64][32];   // prod weights, current 32-h half
    __shared__ float s_w2[64];

    const int t     = threadIdx.x;
    const int blk   = blockIdx.x;
    const int batch = blk / 36;
    int tile        = blk % 36;

    // map tile index -> (a, c) with a <= c over 8x8 tile grid (upper tri)
    int a = 0;
    while (tile >= (NT - a)) { tile -= (NT - a); a++; }
    const int ti0 = a * 32;
    const int tj0 = (a + tile) * 32;

    const float* Ob = O + (size_t)batch * Nn * Dd;

    // ---- Phase 0: load O tiles (coalesced float4) ----
    {
        const float4* Oi4 = reinterpret_cast<const float4*>(Ob + ti0 * Dd);
        const float4* Oj4 = reinterpret_cast<const float4*>(Ob + tj0 * Dd);
        #pragma unroll
        for (int p = 0; p < 2; p++) {
            int v = t + p * 256;            // 512 float4 per tile
            int r = v >> 4, c4 = (v & 15) * 4;
            float4 x = Oi4[v];
            s_oi[r][c4+0] = x.x; s_oi[r][c4+1] = x.y;
            s_oi[r][c4+2] = x.z; s_oi[r][c4+3] = x.w;
            float4 y = Oj4[v];
            s_oj[r][c4+0] = y.x; s_oj[r][c4+1] = y.y;
            s_oj[r][c4+2] = y.z; s_oj[r][c4+3] = y.w;
        }
        if (t < 64) s_w2[t] = W2[t];
    }
    __syncthreads();

    // ---- Phase 1: per-row terms A[i,h] (+b1) and C[j,h] ----
    {
        const int h  = t & 63;
        const int r0 = t >> 6;   // 0..3 (uniform per wave)
        float accA[8], accC[8];
        #pragma unroll
        for (int rr = 0; rr < 8; rr++) { accA[rr] = 0.f; accC[rr] = 0.f; }
        for (int d = 0; d < 64; d++) {
            float wa = W1[d * 64 + h];          // rows 0..63   (Oi)
            float wb = W1[(64 + d) * 64 + h];   // rows 64..127 (Oj)
            #pragma unroll
            for (int rr = 0; rr < 8; rr++) {
                int r = rr * 4 + r0;
                accA[rr] = fmaf(s_oi[r][d], wa, accA[rr]);
                accC[rr] = fmaf(s_oj[r][d], wb, accC[rr]);
            }
        }
        float bb = b1[h];
        #pragma unroll
        for (int rr = 0; rr < 8; rr++) {
            int r = rr * 4 + r0;
            s_A[r][h] = accA[rr] + bb;
            s_C[r][h] = accC[rr];
        }
    }

    // ---- Phase 2: pairwise main loop ----
    const int ti  = t >> 3;         // 0..31
    const int tj4 = (t & 7) * 4;    // 0,4,...,28
    const int i   = ti0 + ti;

    float q[4] = {0.f, 0.f, 0.f, 0.f};

    for (int half = 0; half < 2; half++) {
        __syncthreads();   // protect s_cw/s_dw from previous readers
        // stage W1c/W1d for this 32-h half
        #pragma unroll
        for (int p = 0; p < 2; p++) {
            int v = t + p * 256;               // 512 float4
            int d = v >> 3, h4 = (v & 7) * 4;
            float4 x = *reinterpret_cast<const float4*>(W1 + (128 + d) * 64 + half * 32 + h4);
            *reinterpret_cast<float4*>(&s_cw[d][h4]) = x;
            float4 y = *reinterpret_cast<const float4*>(W1 + (192 + d) * 64 + half * 32 + h4);
            *reinterpret_cast<float4*>(&s_dw[d][h4]) = y;
        }
        __syncthreads();

        for (int hc = 0; hc < 2; hc++) {
            const int hbase = half * 32 + hc * 16;
            float acc[4][16];
            #pragma unroll
            for (int k = 0; k < 4; k++)
                #pragma unroll
                for (int hh = 0; hh < 16; hh++)
                    acc[k][hh] = s_A[ti][hbase + hh] + s_C[tj4 + k][hbase + hh];

            for (int d = 0; d < 64; d++) {
                float oi = s_oi[ti][d];
                float ad[4], pd[4];
                #pragma unroll
                for (int k = 0; k < 4; k++) {
                    float oj = s_oj[tj4 + k][d];
                    float df = oi - oj;
                    ad[k] = fabsf(df);
                    pd[k] = oi * oj;
                }
                const float4* cp = reinterpret_cast<const float4*>(&s_cw[d][hc * 16]);
                const float4* dp = reinterpret_cast<const float4*>(&s_dw[d][hc * 16]);
                #pragma unroll
                for (int g = 0; g < 4; g++) {
                    float4 cv = cp[g];
                    float4 dv = dp[g];
                    #pragma unroll
                    for (int k = 0; k < 4; k++) {
                        acc[k][g*4+0] = fmaf(ad[k], cv.x, fmaf(pd[k], dv.x, acc[k][g*4+0]));
                        acc[k][g*4+1] = fmaf(ad[k], cv.y, fmaf(pd[k], dv.y, acc[k][g*4+1]));
                        acc[k][g*4+2] = fmaf(ad[k], cv.z, fmaf(pd[k], dv.z, acc[k][g*4+2]));
                        acc[k][g*4+3] = fmaf(ad[k], cv.w, fmaf(pd[k], dv.w, acc[k][g*4+3]));
                    }
                }
            }
            // chunk epilogue: relu + W2 dot
            #pragma unroll
            for (int k = 0; k < 4; k++)
                #pragma unroll
                for (int hh = 0; hh < 16; hh++)
                    q[k] = fmaf(fmaxf(acc[k][hh], 0.f), s_w2[hbase + hh], q[k]);
        }
    }

    // ---- write Q for valid pairs (j > i) ----
    const float bb2 = b2[0];
    #pragma unroll
    for (int k = 0; k < 4; k++) {
        int j = tj0 + tj4 + k;
        if (j > i) {
            int m = i * (Nn - 1) - (i * (i - 1)) / 2 + (j - i - 1);
            Q[(size_t)batch * Mm + m] = q[k] + bb2;
        }
    }
}

// ---------------------------------------------------------------------------
// Top-2 + mask kernel: one block per batch.
// ---------------------------------------------------------------------------
__global__ __launch_bounds__(256) void topk_kernel(
    const float* __restrict__ Q, float* __restrict__ mask)
{
    const int b = blockIdx.x;
    const int t = threadIdx.x;
    const float* Qb = Q + (size_t)b * Mm;

    float v1 = -INFINITY, v2 = -INFINITY;
    int   i1 = 0x7fffffff, i2 = 0x7fffffff;
    for (int m = t; m < Mm; m += 256) {
        float v = Qb[m];
        if (v > v1 || (v == v1 && m < i1)) {
            v2 = v1; i2 = i1; v1 = v; i1 = m;
        } else if (v > v2 || (v == v2 && m < i2)) {
            v2 = v; i2 = m;
        }
    }

    __shared__ float sv[512];
    __shared__ int   si[512];
    sv[t] = v1;       si[t] = i1;
    sv[256 + t] = v2; si[256 + t] = i2;
    __syncthreads();

    __shared__ int top0, top1;
    if (t == 0) {
        float a1 = -INFINITY, a2 = -INFINITY;
        int   x1 = -1, x2 = -1;
        for (int s = 0; s < 512; s++) {
            float v = sv[s]; int idx = si[s];
            if (idx == 0x7fffffff) continue;
            if (v > a1 || (v == a1 && idx < x1)) {
                a2 = a1; x2 = x1; a1 = v; x1 = idx;
            } else if (v > a2 || (v == a2 && idx < x2)) {
                a2 = v; x2 = idx;
            }
        }
        top0 = x1; top1 = x2;
    }
    __syncthreads();

    const int k0 = top0, k1 = top1;
    float* mb = mask + (size_t)b * Mm;
    for (int m = t; m < Mm; m += 256) {
        mb[m] = (m == k0 || m == k1) ? 1.0f : 0.0f;
    }
}

extern "C" void kernel_launch(void* const* d_in, const int* in_sizes, int n_in,
                              void* d_out, int out_size, void* d_ws, size_t ws_size,
                              hipStream_t stream) {
    const float* O  = (const float*)d_in[0];
    const float* W1 = (const float*)d_in[1];
    const float* b1 = (const float*)d_in[2];
    const float* W2 = (const float*)d_in[3];
    const float* b2 = (const float*)d_in[4];

    float* Q    = (float*)d_out;
    float* mask = Q + (size_t)Bn * Mm;

    pair_kernel<<<dim3(Bn * 36), dim3(256), 0, stream>>>(O, W1, b1, W2, b2, Q);
    topk_kernel<<<dim3(Bn), dim3(256), 0, stream>>>(Q, mask);
}

// Round 2
// 162.231 us; speedup vs baseline: 1.7995x; 1.7995x over previous
//
#include <hip/hip_runtime.h>
#include <math.h>

#define Bn 16
#define Nn 256
#define Dd 64
#define Mm (Nn*(Nn-1)/2)   /* 32640 */
#define NT 8
#define CHUNK 4080         /* Mm / 8 */

// ---------------------------------------------------------------------------
// Pair kernel: one block = (batch, 32x32 pair tile, h-half of 32).
// 256 threads; thread handles pairs (i = ti0 + (t>>3), j = tj0 + (t&7) + 8k).
// Per-row terms A[i,h], C[j,h] precomputed; inner loop does only the two
// pairwise terms (|Oi-Oj| and Oi*Oj) against staged W1 halves.
// Two h-half blocks atomically accumulate into zero-initialized Q.
// ---------------------------------------------------------------------------
__global__ __launch_bounds__(256, 4) void pair_kernel(
    const float* __restrict__ O,
    const float* __restrict__ W1,
    const float* __restrict__ b1,
    const float* __restrict__ W2,
    const float* __restrict__ b2,
    float* __restrict__ Q)
{
    __shared__ float s_oi[32][68];   // stride 68: 272B rows, 16B-aligned, rows 0..7 -> banks 0,4,..,28
    __shared__ float s_oj[32][68];
    __shared__ float s_A [32][33];   // includes +b1
    __shared__ float s_C [32][33];
    __shared__ float s_cw[64][16];   // |diff| weights, current 16-h chunk
    __shared__ float s_dw[64][16];   // prod weights, current 16-h chunk
    __shared__ float s_w2[32];

    const int t     = threadIdx.x;
    const int blk   = blockIdx.x;
    const int hhalf = blk & 1;
    int rest        = blk >> 1;
    const int batch = rest / 36;
    int tile        = rest % 36;

    int a = 0;
    while (tile >= (NT - a)) { tile -= (NT - a); a++; }
    const int ti0 = a * 32;
    const int tj0 = (a + tile) * 32;
    const int hbase0 = hhalf * 32;

    const float* Ob = O + (size_t)batch * Nn * Dd;

    // ---- Phase 0: load O tiles (coalesced float4) ----
    {
        const float4* Oi4 = reinterpret_cast<const float4*>(Ob + ti0 * Dd);
        const float4* Oj4 = reinterpret_cast<const float4*>(Ob + tj0 * Dd);
        #pragma unroll
        for (int p = 0; p < 2; p++) {
            int v = t + p * 256;            // 512 float4 per tile
            int r = v >> 4, c4 = (v & 15) * 4;
            *reinterpret_cast<float4*>(&s_oi[r][c4]) = Oi4[v];
            *reinterpret_cast<float4*>(&s_oj[r][c4]) = Oj4[v];
        }
        if (t < 32) s_w2[t] = W2[hbase0 + t];
    }
    __syncthreads();

    // ---- Phase 1: per-row terms A[i,h] (+b1) and C[j,h] for this h-half ----
    {
        const int h  = t & 31;
        const int r0 = t >> 5;              // 0..7
        const int hg = hbase0 + h;
        float accA[4] = {0.f,0.f,0.f,0.f};
        float accC[4] = {0.f,0.f,0.f,0.f};
        for (int d = 0; d < 64; d++) {
            float wa = W1[d * 64 + hg];          // rows 0..63   (Oi)
            float wb = W1[(64 + d) * 64 + hg];   // rows 64..127 (Oj)
            #pragma unroll
            for (int rr = 0; rr < 4; rr++) {
                int r = r0 + rr * 8;
                accA[rr] = fmaf(s_oi[r][d], wa, accA[rr]);
                accC[rr] = fmaf(s_oj[r][d], wb, accC[rr]);
            }
        }
        float bb = b1[hg];
        #pragma unroll
        for (int rr = 0; rr < 4; rr++) {
            int r = r0 + rr * 8;
            s_A[r][h] = accA[rr] + bb;
            s_C[r][h] = accC[rr];
        }
    }

    // ---- Phase 2: pairwise main loop ----
    const int ti  = t >> 3;       // 0..31  (i row)
    const int tj1 = t & 7;        // j rows: tj1, tj1+8, tj1+16, tj1+24
    const int i   = ti0 + ti;

    float q[4] = {0.f, 0.f, 0.f, 0.f};

    for (int hc = 0; hc < 2; hc++) {
        __syncthreads();   // protect s_cw/s_dw from previous chunk's readers
        {
            int d  = t >> 2, c4 = (t & 3) * 4;   // linear LDS write
            int col = hbase0 + hc * 16 + c4;
            *reinterpret_cast<float4*>(&s_cw[d][c4]) =
                *reinterpret_cast<const float4*>(&W1[(128 + d) * 64 + col]);
            *reinterpret_cast<float4*>(&s_dw[d][c4]) =
                *reinterpret_cast<const float4*>(&W1[(192 + d) * 64 + col]);
        }
        __syncthreads();

        float acc[4][16];
        #pragma unroll
        for (int k = 0; k < 4; k++) {
            #pragma unroll
            for (int hh = 0; hh < 16; hh++)
                acc[k][hh] = s_A[ti][hc * 16 + hh] + s_C[tj1 + 8 * k][hc * 16 + hh];
        }

        for (int dg = 0; dg < 16; dg++) {
            float4 oi4 = *reinterpret_cast<const float4*>(&s_oi[ti][dg * 4]);
            float4 oj4[4];
            #pragma unroll
            for (int k = 0; k < 4; k++)
                oj4[k] = *reinterpret_cast<const float4*>(&s_oj[tj1 + 8 * k][dg * 4]);
            const float* oif = reinterpret_cast<const float*>(&oi4);
            #pragma unroll
            for (int dd = 0; dd < 4; dd++) {
                const int d = dg * 4 + dd;
                const float oid = oif[dd];
                float ad[4], pd[4];
                #pragma unroll
                for (int k = 0; k < 4; k++) {
                    float ojd = reinterpret_cast<const float*>(&oj4[k])[dd];
                    ad[k] = fabsf(oid - ojd);
                    pd[k] = oid * ojd;
                }
                const float4* cp = reinterpret_cast<const float4*>(&s_cw[d][0]);
                const float4* dp = reinterpret_cast<const float4*>(&s_dw[d][0]);
                #pragma unroll
                for (int g = 0; g < 4; g++) {
                    float4 cv = cp[g];
                    float4 dv = dp[g];
                    #pragma unroll
                    for (int k = 0; k < 4; k++) {
                        acc[k][g*4+0] = fmaf(ad[k], cv.x, fmaf(pd[k], dv.x, acc[k][g*4+0]));
                        acc[k][g*4+1] = fmaf(ad[k], cv.y, fmaf(pd[k], dv.y, acc[k][g*4+1]));
                        acc[k][g*4+2] = fmaf(ad[k], cv.z, fmaf(pd[k], dv.z, acc[k][g*4+2]));
                        acc[k][g*4+3] = fmaf(ad[k], cv.w, fmaf(pd[k], dv.w, acc[k][g*4+3]));
                    }
                }
            }
        }
        // chunk epilogue: relu + W2 dot
        #pragma unroll
        for (int k = 0; k < 4; k++)
            #pragma unroll
            for (int hh = 0; hh < 16; hh++)
                q[k] = fmaf(fmaxf(acc[k][hh], 0.f), s_w2[hc * 16 + hh], q[k]);
    }

    // ---- accumulate partial Q (two h-halves add deterministically) ----
    const float badd = hhalf ? 0.f : b2[0];
    #pragma unroll
    for (int k = 0; k < 4; k++) {
        int j = tj0 + tj1 + 8 * k;
        if (j > i) {
            int m = i * (Nn - 1) - (i * (i - 1)) / 2 + (j - i - 1);
            atomicAdd(&Q[(size_t)batch * Mm + m], q[k] + badd);
        }
    }
}

// ---------------------------------------------------------------------------
// Top-2 stage 1: grid (B x 8), per-chunk top-2 -> ws.
// Comparator is lexicographic (value, -index) to match jax.lax.top_k ties.
// ---------------------------------------------------------------------------
__global__ __launch_bounds__(256) void topk_stage1(
    const float* __restrict__ Q, float* __restrict__ ws)
{
    const int b = blockIdx.x >> 3;
    const int c = blockIdx.x & 7;
    const int t = threadIdx.x;
    const float* Qb = Q + (size_t)b * Mm;
    const int m0 = c * CHUNK;

    float v1 = -INFINITY, v2 = -INFINITY;
    int   i1 = 0x7fffffff, i2 = 0x7fffffff;
    for (int m = m0 + t; m < m0 + CHUNK; m += 256) {
        float v = Qb[m];                 // m ascending: ties keep lower index
        if (v > v1)      { v2 = v1; i2 = i1; v1 = v; i1 = m; }
        else if (v > v2) { v2 = v;  i2 = m; }
    }

    __shared__ float sv[512];
    __shared__ int   si[512];
    sv[t] = v1;       si[t] = i1;
    sv[256 + t] = v2; si[256 + t] = i2;
    __syncthreads();

    __shared__ float sv2[128];
    __shared__ int   si2[128];
    if (t < 64) {
        float a1 = -INFINITY, a2 = -INFINITY;
        int   x1 = 0x7fffffff, x2 = 0x7fffffff;
        for (int e = t; e < 512; e += 64) {
            float v = sv[e]; int idx = si[e];
            if (v > a1 || (v == a1 && idx < x1)) { a2 = a1; x2 = x1; a1 = v; x1 = idx; }
            else if (v > a2 || (v == a2 && idx < x2)) { a2 = v; x2 = idx; }
        }
        sv2[t] = a1;      si2[t] = x1;
        sv2[64 + t] = a2; si2[64 + t] = x2;
    }
    __syncthreads();

    if (t == 0) {
        float a1 = -INFINITY, a2 = -INFINITY;
        int   x1 = 0x7fffffff, x2 = 0x7fffffff;
        for (int e = 0; e < 128; e++) {
            float v = sv2[e]; int idx = si2[e];
            if (v > a1 || (v == a1 && idx < x1)) { a2 = a1; x2 = x1; a1 = v; x1 = idx; }
            else if (v > a2 || (v == a2 && idx < x2)) { a2 = v; x2 = idx; }
        }
        float* w = ws + (size_t)(b * 8 + c) * 4;
        w[0] = a1; w[1] = a2;
        w[2] = __int_as_float(x1); w[3] = __int_as_float(x2);
    }
}

// ---------------------------------------------------------------------------
// Stage 2: grid (B x 8); each block reduces the 16 candidates (redundantly)
// and writes its 4080-entry mask slice.
// ---------------------------------------------------------------------------
__global__ __launch_bounds__(256) void mask_kernel(
    const float* __restrict__ ws, float* __restrict__ mask)
{
    const int b = blockIdx.x >> 3;
    const int c = blockIdx.x & 7;
    const int t = threadIdx.x;

    __shared__ int sk0, sk1;
    if (t == 0) {
        float a1 = -INFINITY, a2 = -INFINITY;
        int   x1 = 0x7fffffff, x2 = 0x7fffffff;
        for (int e = 0; e < 16; e++) {
            const float* w = ws + (size_t)(b * 8 + (e >> 1)) * 4;
            float v  = w[e & 1];
            int  idx = __float_as_int(w[2 + (e & 1)]);
            if (v > a1 || (v == a1 && idx < x1)) { a2 = a1; x2 = x1; a1 = v; x1 = idx; }
            else if (v > a2 || (v == a2 && idx < x2)) { a2 = v; x2 = idx; }
        }
        sk0 = x1; sk1 = x2;
    }
    __syncthreads();

    const int k0 = sk0, k1 = sk1;
    float* mb = mask + (size_t)b * Mm;
    const int m0 = c * CHUNK;
    for (int m = m0 + t; m < m0 + CHUNK; m += 256)
        mb[m] = (m == k0 || m == k1) ? 1.0f : 0.0f;
}

extern "C" void kernel_launch(void* const* d_in, const int* in_sizes, int n_in,
                              void* d_out, int out_size, void* d_ws, size_t ws_size,
                              hipStream_t stream) {
    const float* O  = (const float*)d_in[0];
    const float* W1 = (const float*)d_in[1];
    const float* b1 = (const float*)d_in[2];
    const float* W2 = (const float*)d_in[3];
    const float* b2 = (const float*)d_in[4];

    float* Q    = (float*)d_out;
    float* mask = Q + (size_t)Bn * Mm;
    float* ws   = (float*)d_ws;

    hipMemsetAsync(d_out, 0, (size_t)Bn * Mm * sizeof(float), stream);
    pair_kernel<<<dim3(Bn * 36 * 2), dim3(256), 0, stream>>>(O, W1, b1, W2, b2, Q);
    topk_stage1<<<dim3(Bn * 8), dim3(256), 0, stream>>>(Q, ws);
    mask_kernel<<<dim3(Bn * 8), dim3(256), 0, stream>>>(ws, mask);
}

// Round 4
// 59.751 us; speedup vs baseline: 4.8858x; 2.7151x over previous
//
#include <hip/hip_runtime.h>
#include <math.h>

#define Bn 16
#define Nn 256
#define Dd 64
#define Mm (Nn*(Nn-1)/2)   /* 32640 */
#define NT 8
#define CHUNK 4080         /* Mm / 8 */

typedef __attribute__((ext_vector_type(8))) short bf16x8;
typedef __attribute__((ext_vector_type(4))) short short4v;
typedef __attribute__((ext_vector_type(4))) float f32x4;

typedef union { bf16x8 v; short s[8]; __bf16 h[8]; } F8;
typedef union { short4v v; __bf16 h[4]; } F4;

#define MFMA(acc, a, b) \
  acc = __builtin_amdgcn_mfma_f32_16x16x32_bf16((a), (b), (acc), 0, 0, 0)

__device__ __forceinline__ void top2_update(float v, int m,
    float& v1, int& i1, float& v2, int& i2)
{
  bool c1 = (v > v1) || (v == v1 && m < i1);
  bool c2 = (v > v2) || (v == v2 && m < i2);
  float nv2 = c1 ? v1 : (c2 ? v : v2);
  int   ni2 = c1 ? i1 : (c2 ? m : i2);
  v1 = c1 ? v : v1;  i1 = c1 ? m : i1;
  v2 = nv2;          i2 = ni2;
}

// ---------------------------------------------------------------------------
// Pair kernel (MFMA): one block = (batch, 32x32 pair tile), 256 thr (4 waves).
// Phase 1: A[i,h]=Oi@W1a+b1, C[j,h]=Oj@W1b via MFMA -> LDS (transposed).
// Main: wave wv owns i-rows wv*8..wv*8+7; per (i, jh): acc init A+C, A-frags
// built in-reg from |Oi-Oj| and Oi*Oj (bf16), 16 MFMA vs hoisted W1c/W1d
// frags, epilogue relu+W2 dot + width-16 butterfly -> q tile in LDS.
// Final: coalesced Q store + block top-2 candidates -> cand.
// LDS total 64576 B (<= 64 KB).
// ---------------------------------------------------------------------------
__global__ __launch_bounds__(256, 2) void pair_kernel(
    const float* __restrict__ O,
    const float* __restrict__ W1,
    const float* __restrict__ b1,
    const float* __restrict__ W2,
    const float* __restrict__ b2,
    float* __restrict__ Q,
    float* __restrict__ cand)
{
  __shared__ __align__(16) unsigned short wt[64][264];  // W1^T bf16 [h][k], 528B rows
  __shared__ __align__(16) unsigned short s_oi[32][72]; // bf16, 144B rows
  __shared__ __align__(16) unsigned short s_oj[32][72];
  __shared__ float s_AT[64][33];   // A^T [h][i], includes +b1
  __shared__ float s_CT[64][33];   // C^T [h][j]
  __shared__ float s_q [32][36];   // 144B rows (16B aligned)
  __shared__ float s_red[4][4];

  const int t  = threadIdx.x;
  const int l  = t & 63, wv = t >> 6;
  const int lo = l & 15, g = l >> 4;

  const int blk   = blockIdx.x;
  const int batch = blk / 36;
  int tile        = blk % 36;
  int a = 0;
  while (tile >= (NT - a)) { tile -= NT - a; ++a; }
  const int ti0 = a * 32, tj0 = (a + tile) * 32;
  const bool diag = (tile == 0);

  const float* Ob = O + (size_t)batch * Nn * Dd;

  // ---- stage O tiles as bf16 (coalesced reads, 8B LDS writes) ----
  {
    const float4* Oi4 = (const float4*)(Ob + ti0 * Dd);
    const float4* Oj4 = (const float4*)(Ob + tj0 * Dd);
    #pragma unroll
    for (int p = 0; p < 2; ++p) {
      int v = t + p * 256;            // 512 float4 per tile
      int r = v >> 4, c4 = (v & 15) * 4;
      float4 x = Oi4[v];
      F4 ai; ai.h[0] = (__bf16)x.x; ai.h[1] = (__bf16)x.y;
             ai.h[2] = (__bf16)x.z; ai.h[3] = (__bf16)x.w;
      *(short4v*)&s_oi[r][c4] = ai.v;
      float4 y = Oj4[v];
      F4 aj; aj.h[0] = (__bf16)y.x; aj.h[1] = (__bf16)y.y;
             aj.h[2] = (__bf16)y.z; aj.h[3] = (__bf16)y.w;
      *(short4v*)&s_oj[r][c4] = aj.v;
    }
  }
  // ---- stage W1^T as bf16 (coalesced reads, 16B LDS writes) ----
  {
    #pragma unroll
    for (int it = 0; it < 8; ++it) {
      int h  = t & 63;
      int gq = (t >> 6) + 4 * it;     // granule 0..31
      int k0 = gq * 8;
      F8 wk;
      #pragma unroll
      for (int e = 0; e < 8; ++e)
        wk.h[e] = (__bf16)W1[(k0 + e) * 64 + h];
      *(bf16x8*)&wt[h][k0] = wk.v;
    }
  }
  __syncthreads();

  // ---- Phase 1: A = Oi@W1a (+b1), C = Oj@W1b via MFMA ----
  {
    const int  mf  = wv & 1;
    const bool isA = (wv < 2);
    const int  bk  = isA ? 0 : 64;
    const unsigned short (*src)[72] = isA ? s_oi : s_oj;

    F8 bf[2][4];
    #pragma unroll
    for (int ks = 0; ks < 2; ++ks)
      #pragma unroll
      for (int nf = 0; nf < 4; ++nf)
        bf[ks][nf].v = *(const bf16x8*)&wt[nf * 16 + lo][bk + ks * 32 + g * 8];

    F8 aop[2];
    #pragma unroll
    for (int ks = 0; ks < 2; ++ks)
      aop[ks].v = *(const bf16x8*)&src[mf * 16 + lo][ks * 32 + g * 8];

    f32x4 ac0 = {0.f,0.f,0.f,0.f}, ac1 = {0.f,0.f,0.f,0.f},
          ac2 = {0.f,0.f,0.f,0.f}, ac3 = {0.f,0.f,0.f,0.f};
    #pragma unroll
    for (int ks = 0; ks < 2; ++ks) {
      MFMA(ac0, aop[ks].v, bf[ks][0].v);
      MFMA(ac1, aop[ks].v, bf[ks][1].v);
      MFMA(ac2, aop[ks].v, bf[ks][2].v);
      MFMA(ac3, aop[ks].v, bf[ks][3].v);
    }

    float bad0 = 0.f, bad1 = 0.f, bad2 = 0.f, bad3 = 0.f;
    if (isA) {
      bad0 = b1[lo]; bad1 = b1[16 + lo]; bad2 = b1[32 + lo]; bad3 = b1[48 + lo];
    }
    float (*dst)[33] = isA ? s_AT : s_CT;
    const int rbase = mf * 16 + g * 4;
    #pragma unroll
    for (int r = 0; r < 4; ++r) {
      dst[lo     ][rbase + r] = ac0[r] + bad0;
      dst[16 + lo][rbase + r] = ac1[r] + bad1;
      dst[32 + lo][rbase + r] = ac2[r] + bad2;
      dst[48 + lo][rbase + r] = ac3[r] + bad3;
    }
  }
  __syncthreads();

  // ---- main loop hoists ----
  F8 bfr[4][4];                       // W1c/W1d frags: k = 128 + ks*32 + g*8
  #pragma unroll
  for (int ks = 0; ks < 4; ++ks)
    #pragma unroll
    for (int nf = 0; nf < 4; ++nf)
      bfr[ks][nf].v = *(const bf16x8*)&wt[nf * 16 + lo][128 + ks * 32 + g * 8];

  float ojv[2][16];
  #pragma unroll
  for (int jh = 0; jh < 2; ++jh) {
    F8 u0, u1;
    u0.v = *(const bf16x8*)&s_oj[jh * 16 + lo][g * 8];
    u1.v = *(const bf16x8*)&s_oj[jh * 16 + lo][32 + g * 8];
    #pragma unroll
    for (int e = 0; e < 8; ++e) {
      ojv[jh][e]     = (float)u0.h[e];
      ojv[jh][8 + e] = (float)u1.h[e];
    }
  }

  float cin[2][4][4];
  #pragma unroll
  for (int jh = 0; jh < 2; ++jh)
    #pragma unroll
    for (int nf = 0; nf < 4; ++nf)
      #pragma unroll
      for (int r = 0; r < 4; ++r)
        cin[jh][nf][r] = s_CT[nf * 16 + lo][jh * 16 + g * 4 + r];

  float w2v[4] = { W2[lo], W2[16 + lo], W2[32 + lo], W2[48 + lo] };

  for (int ii = 0; ii < 8; ++ii) {
    const int iL = wv * 8 + ii;
    float oiv[16];
    {
      F8 u0, u1;
      u0.v = *(const bf16x8*)&s_oi[iL][g * 8];
      u1.v = *(const bf16x8*)&s_oi[iL][32 + g * 8];
      #pragma unroll
      for (int e = 0; e < 8; ++e) {
        oiv[e]     = (float)u0.h[e];
        oiv[8 + e] = (float)u1.h[e];
      }
    }
    float ah[4] = { s_AT[lo][iL], s_AT[16 + lo][iL],
                    s_AT[32 + lo][iL], s_AT[48 + lo][iL] };

    #pragma unroll
    for (int jh = 0; jh < 2; ++jh) {
      f32x4 acc0, acc1, acc2, acc3;
      #pragma unroll
      for (int r = 0; r < 4; ++r) {
        acc0[r] = cin[jh][0][r] + ah[0];
        acc1[r] = cin[jh][1][r] + ah[1];
        acc2[r] = cin[jh][2][r] + ah[2];
        acc3[r] = cin[jh][3][r] + ah[3];
      }

      F8 a0, a1, a2, a3;   // feature k-slices 0..3
      #pragma unroll
      for (int e = 0; e < 8; ++e) {
        float p0 = ojv[jh][e], p1 = ojv[jh][8 + e];
        a0.h[e] = (__bf16)fabsf(oiv[e]     - p0);
        a1.h[e] = (__bf16)fabsf(oiv[8 + e] - p1);
        a2.h[e] = (__bf16)(oiv[e]     * p0);
        a3.h[e] = (__bf16)(oiv[8 + e] * p1);
      }
      MFMA(acc0, a0.v, bfr[0][0].v); MFMA(acc1, a0.v, bfr[0][1].v);
      MFMA(acc2, a0.v, bfr[0][2].v); MFMA(acc3, a0.v, bfr[0][3].v);
      MFMA(acc0, a1.v, bfr[1][0].v); MFMA(acc1, a1.v, bfr[1][1].v);
      MFMA(acc2, a1.v, bfr[1][2].v); MFMA(acc3, a1.v, bfr[1][3].v);
      MFMA(acc0, a2.v, bfr[2][0].v); MFMA(acc1, a2.v, bfr[2][1].v);
      MFMA(acc2, a2.v, bfr[2][2].v); MFMA(acc3, a2.v, bfr[2][3].v);
      MFMA(acc0, a3.v, bfr[3][0].v); MFMA(acc1, a3.v, bfr[3][1].v);
      MFMA(acc2, a3.v, bfr[3][2].v); MFMA(acc3, a3.v, bfr[3][3].v);

      float val0, val1, val2, val3;
      val0 = fmaxf(acc0[0], 0.f) * w2v[0] + fmaxf(acc1[0], 0.f) * w2v[1]
           + fmaxf(acc2[0], 0.f) * w2v[2] + fmaxf(acc3[0], 0.f) * w2v[3];
      val1 = fmaxf(acc0[1], 0.f) * w2v[0] + fmaxf(acc1[1], 0.f) * w2v[1]
           + fmaxf(acc2[1], 0.f) * w2v[2] + fmaxf(acc3[1], 0.f) * w2v[3];
      val2 = fmaxf(acc0[2], 0.f) * w2v[0] + fmaxf(acc1[2], 0.f) * w2v[1]
           + fmaxf(acc2[2], 0.f) * w2v[2] + fmaxf(acc3[2], 0.f) * w2v[3];
      val3 = fmaxf(acc0[3], 0.f) * w2v[0] + fmaxf(acc1[3], 0.f) * w2v[1]
           + fmaxf(acc2[3], 0.f) * w2v[2] + fmaxf(acc3[3], 0.f) * w2v[3];
      #pragma unroll
      for (int s = 1; s < 16; s <<= 1) {
        val0 += __shfl_xor(val0, s, 16);
        val1 += __shfl_xor(val1, s, 16);
        val2 += __shfl_xor(val2, s, 16);
        val3 += __shfl_xor(val3, s, 16);
      }
      float sel = val0;
      sel = (lo == 1) ? val1 : sel;
      sel = (lo == 2) ? val2 : sel;
      sel = (lo == 3) ? val3 : sel;
      if (lo < 4) s_q[iL][jh * 16 + g * 4 + lo] = sel;
    }
  }
  __syncthreads();

  // ---- final: Q store + block top-2 ----
  {
    const float b2v = b2[0];
    const int row = t >> 3, c4 = (t & 7) * 4;
    const int i = ti0 + row;
    float4 q4 = *(const float4*)&s_q[row][c4];
    const int K0 = i * (Nn - 1) - (i * (i - 1)) / 2 + tj0 + c4 - i - 1;
    float v1 = -INFINITY, v2 = -INFINITY;
    int   i1 = 0x7fffffff, i2 = 0x7fffffff;
    float qe[4] = { q4.x + b2v, q4.y + b2v, q4.z + b2v, q4.w + b2v };
    #pragma unroll
    for (int e = 0; e < 4; ++e) {
      int j = tj0 + c4 + e;
      bool valid = !diag || (j > i);
      if (valid) {
        Q[(size_t)batch * Mm + K0 + e] = qe[e];
        top2_update(qe[e], K0 + e, v1, i1, v2, i2);
      }
    }
    #pragma unroll
    for (int s = 1; s < 64; s <<= 1) {
      float u1 = __shfl_xor(v1, s); int j1 = __shfl_xor(i1, s);
      float u2 = __shfl_xor(v2, s); int j2 = __shfl_xor(i2, s);
      top2_update(u1, j1, v1, i1, v2, i2);
      top2_update(u2, j2, v1, i1, v2, i2);
    }
    if (l == 0) {
      s_red[wv][0] = v1; s_red[wv][1] = __int_as_float(i1);
      s_red[wv][2] = v2; s_red[wv][3] = __int_as_float(i2);
    }
    __syncthreads();
    if (t == 0) {
      float a1 = s_red[0][0]; int x1 = __float_as_int(s_red[0][1]);
      float a2 = s_red[0][2]; int x2 = __float_as_int(s_red[0][3]);
      #pragma unroll
      for (int e = 1; e < 4; ++e) {
        top2_update(s_red[e][0], __float_as_int(s_red[e][1]), a1, x1, a2, x2);
        top2_update(s_red[e][2], __float_as_int(s_red[e][3]), a1, x1, a2, x2);
      }
      float* cp = cand + (size_t)blk * 4;
      cp[0] = a1; cp[1] = __int_as_float(x1);
      cp[2] = a2; cp[3] = __int_as_float(x2);
    }
  }
}

// ---------------------------------------------------------------------------
// Rank kernel: per batch, merge 72 candidates -> top-8 (by bf16 Q), recompute
// those 8 exactly in fp32 from global O/W1, pick exact top-2 (jax tie rule).
// ---------------------------------------------------------------------------
__global__ __launch_bounds__(256) void rank_kernel(
    const float* __restrict__ O, const float* __restrict__ W1,
    const float* __restrict__ b1, const float* __restrict__ W2,
    const float* __restrict__ cand, int* __restrict__ ws2)
{
  const int b = blockIdx.x;
  const int t = threadIdx.x;
  __shared__ float s_cv[72];
  __shared__ int   s_ci[72];
  __shared__ int   s_m[8];
  __shared__ int   s_ij[8][2];
  __shared__ float s_or[8][2][64];
  __shared__ float s_part[8][32];
  __shared__ float s_qe[8];

  if (t < 72) {
    const float* cp = cand + (size_t)(b * 36 + (t >> 1)) * 4;
    s_cv[t] = cp[(t & 1) * 2];
    s_ci[t] = __float_as_int(cp[(t & 1) * 2 + 1]);
  }
  __syncthreads();
  if (t < 72) {
    float v = s_cv[t]; int m = s_ci[t];
    int rank = 0;
    for (int e = 0; e < 72; ++e) {
      float u = s_cv[e]; int n = s_ci[e];
      rank += (u > v || (u == v && n < m)) ? 1 : 0;
    }
    if (rank < 8) s_m[rank] = m;
  }
  __syncthreads();
  if (t < 16) {
    int m = s_m[t >> 1];
    int i = 0, rem = m;
    while (rem >= Nn - 1 - i) { rem -= Nn - 1 - i; ++i; }
    int j = i + 1 + rem;
    s_ij[t >> 1][t & 1] = (t & 1) ? j : i;
  }
  __syncthreads();
  {
    int c = t >> 5, rr = (t >> 4) & 1, c4 = (t & 15) * 4;
    int row = s_ij[c][rr];
    *(float4*)&s_or[c][rr][c4] = *(const float4*)&O[((size_t)b * Nn + row) * Dd + c4];
  }
  __syncthreads();
  {
    int c = t >> 5, hh = t & 31, h2 = hh * 2;
    float z0 = b1[h2], z1 = b1[h2 + 1];
    for (int d = 0; d < 64; ++d) {
      float oi = s_or[c][0][d], oj = s_or[c][1][d];
      float f3 = fabsf(oi - oj), f4 = oi * oj;
      float2 wa = *(const float2*)&W1[(d      ) * 64 + h2];
      float2 wb = *(const float2*)&W1[(64 + d ) * 64 + h2];
      float2 wc = *(const float2*)&W1[(128 + d) * 64 + h2];
      float2 wd = *(const float2*)&W1[(192 + d) * 64 + h2];
      z0 += oi * wa.x + oj * wb.x + f3 * wc.x + f4 * wd.x;
      z1 += oi * wa.y + oj * wb.y + f3 * wc.y + f4 * wd.y;
    }
    s_part[c][hh] = fmaxf(z0, 0.f) * W2[h2] + fmaxf(z1, 0.f) * W2[h2 + 1];
  }
  __syncthreads();
  if (t < 8) {
    float s = 0.f;
    for (int e = 0; e < 32; ++e) s += s_part[t][e];
    s_qe[t] = s;
  }
  __syncthreads();
  if (t == 0) {
    float v1 = -INFINITY, v2 = -INFINITY;
    int   i1 = 0x7fffffff, i2 = 0x7fffffff;
    for (int e = 0; e < 8; ++e)
      top2_update(s_qe[e], s_m[e], v1, i1, v2, i2);
    ws2[b * 2] = i1; ws2[b * 2 + 1] = i2;
  }
}

// ---------------------------------------------------------------------------
// Mask kernel
// ---------------------------------------------------------------------------
__global__ __launch_bounds__(256) void mask_kernel(
    const int* __restrict__ ws2, float* __restrict__ mask)
{
  const int b = blockIdx.x >> 3, cch = blockIdx.x & 7, t = threadIdx.x;
  const int k0 = ws2[b * 2], k1 = ws2[b * 2 + 1];
  float* mb = mask + (size_t)b * Mm;
  const int m0 = cch * CHUNK;
  for (int m = m0 + t; m < m0 + CHUNK; m += 256)
    mb[m] = (m == k0 || m == k1) ? 1.0f : 0.0f;
}

extern "C" void kernel_launch(void* const* d_in, const int* in_sizes, int n_in,
                              void* d_out, int out_size, void* d_ws, size_t ws_size,
                              hipStream_t stream) {
  const float* O  = (const float*)d_in[0];
  const float* W1 = (const float*)d_in[1];
  const float* b1 = (const float*)d_in[2];
  const float* W2 = (const float*)d_in[3];
  const float* b2 = (const float*)d_in[4];

  float* Q    = (float*)d_out;
  float* mask = Q + (size_t)Bn * Mm;
  float* cand = (float*)d_ws;
  int*   ws2  = (int*)d_ws + 4096;

  pair_kernel<<<dim3(Bn * 36), dim3(256), 0, stream>>>(O, W1, b1, W2, b2, Q, cand);
  rank_kernel<<<dim3(Bn), dim3(256), 0, stream>>>(O, W1, b1, W2, cand, ws2);
  mask_kernel<<<dim3(Bn * 8), dim3(256), 0, stream>>>(ws2, mask);
}

// Round 5
// 59.446 us; speedup vs baseline: 4.9108x; 1.0051x over previous
//
#include <hip/hip_runtime.h>
#include <math.h>

#define Bn 16
#define Nn 256
#define Mm (Nn*(Nn-1)/2)   /* 32640 */
#define CHUNK 4080         /* Mm / 8 */

typedef __attribute__((ext_vector_type(8))) short bf16x8;
typedef __attribute__((ext_vector_type(4))) short short4v;
typedef __attribute__((ext_vector_type(4))) float f32x4;

typedef union { bf16x8 v; short s[8]; __bf16 h[8]; } F8;
typedef union { short4v v; __bf16 h[4]; } F4;

#define MFMA(acc, a, b) \
  acc = __builtin_amdgcn_mfma_f32_16x16x32_bf16((a), (b), (acc), 0, 0, 0)

__device__ __forceinline__ void top2_update(float v, int m,
    float& v1, int& i1, float& v2, int& i2)
{
  bool c1 = (v > v1) || (v == v1 && m < i1);
  bool c2 = (v > v2) || (v == v2 && m < i2);
  float nv2 = c1 ? v1 : (c2 ? v : v2);
  int   ni2 = c1 ? i1 : (c2 ? m : i2);
  v1 = c1 ? v : v1;  i1 = c1 ? m : i1;
  v2 = nv2;          i2 = ni2;
}

// ---------------------------------------------------------------------------
// Prep: W1 (256k x 64h f32) -> wtg bf16 [h][k] (64 x 256), RNE cast.
// ---------------------------------------------------------------------------
__global__ __launch_bounds__(256) void prep_w1t(
    const float* __restrict__ W1, unsigned short* __restrict__ wtg)
{
  const int h = blockIdx.x;      // 0..63
  const int k = threadIdx.x;     // 0..255
  __bf16 b = (__bf16)W1[k * 64 + h];
  wtg[h * 256 + k] = *(unsigned short*)&b;
}

// ---------------------------------------------------------------------------
// Pair kernel: one block = (batch, 16x32 pair tile), 256 thr (4 waves).
// Swapped-operand MFMA: A = W1^T fragments (h x k, from global wtg),
// B = feature fragments (k x pair). Output C[h][pair].
// Wave wv owns i-rows wv*4..wv*4+3; per (ii,jh): 16 MFMA, epilogue is
// per-lane relu+W2 partial + 2 shfl_xor.
// LDS ~23 KB.
// ---------------------------------------------------------------------------
__global__ __launch_bounds__(256, 3) void pair_kernel(
    const float* __restrict__ O,
    const float* __restrict__ b1,
    const float* __restrict__ W2,
    const float* __restrict__ b2,
    const unsigned short* __restrict__ wtg,
    float* __restrict__ Q,
    float* __restrict__ cand)
{
  __shared__ __align__(16) unsigned short s_oi[16][72]; // bf16, 144B rows
  __shared__ __align__(16) unsigned short s_oj[32][72];
  __shared__ float s_A[16][68];   // A[i][h] (+b1), 272B rows
  __shared__ float s_C[32][68];   // C[j][h]
  __shared__ float s_q[16][36];
  __shared__ float s_w2[64];
  __shared__ float s_red[4][4];

  const int t  = threadIdx.x;
  const int l  = t & 63, wv = t >> 6;
  const int lo = l & 15, g = l >> 4;

  const int blk   = blockIdx.x;
  const int batch = blk / 72;
  int tl          = blk % 72;
  int a = 0;
  while (tl >= 8 - (a >> 1)) { tl -= 8 - (a >> 1); ++a; }
  const int c   = (a >> 1) + tl;
  const int ti0 = a * 16, tj0 = c * 32;

  const float* Ob = O + (size_t)batch * Nn * 64;

  // ---- stage O tiles as bf16 ----
  {
    const float4* Oi4 = (const float4*)(Ob + ti0 * 64);
    {
      int r = t >> 4, c4 = (t & 15) * 4;
      float4 x = Oi4[t];
      F4 p; p.h[0] = (__bf16)x.x; p.h[1] = (__bf16)x.y;
            p.h[2] = (__bf16)x.z; p.h[3] = (__bf16)x.w;
      *(short4v*)&s_oi[r][c4] = p.v;
    }
    const float4* Oj4 = (const float4*)(Ob + tj0 * 64);
    #pragma unroll
    for (int p2 = 0; p2 < 2; ++p2) {
      int v = t + p2 * 256;
      int r = v >> 4, c4 = (v & 15) * 4;
      float4 x = Oj4[v];
      F4 p; p.h[0] = (__bf16)x.x; p.h[1] = (__bf16)x.y;
            p.h[2] = (__bf16)x.z; p.h[3] = (__bf16)x.w;
      *(short4v*)&s_oj[r][c4] = p.v;
    }
    if (t < 64) s_w2[t] = W2[t];
  }
  __syncthreads();

  // ---- Phase 1: A[i][h] = Oi@W1a + b1 ; C[j][h] = Oj@W1b ----
  if (wv < 2) {
    #pragma unroll
    for (int nn = 0; nn < 2; ++nn) {
      const int nf = wv * 2 + nn;
      f32x4 ac = {0.f, 0.f, 0.f, 0.f};
      #pragma unroll
      for (int ks = 0; ks < 2; ++ks) {
        F8 aop; aop.v = *(const bf16x8*)&s_oi[lo][ks * 32 + g * 8];
        F8 bop; bop.v = *(const bf16x8*)&wtg[(nf * 16 + lo) * 256 + ks * 32 + g * 8];
        MFMA(ac, aop.v, bop.v);
      }
      const float bb = b1[nf * 16 + lo];
      #pragma unroll
      for (int r = 0; r < 4; ++r)
        s_A[g * 4 + r][nf * 16 + lo] = ac[r] + bb;
    }
  } else {
    const int mf = wv - 2;
    #pragma unroll
    for (int nf = 0; nf < 4; ++nf) {
      f32x4 ac = {0.f, 0.f, 0.f, 0.f};
      #pragma unroll
      for (int ks = 0; ks < 2; ++ks) {
        F8 aop; aop.v = *(const bf16x8*)&s_oj[mf * 16 + lo][ks * 32 + g * 8];
        F8 bop; bop.v = *(const bf16x8*)&wtg[(nf * 16 + lo) * 256 + 64 + ks * 32 + g * 8];
        MFMA(ac, aop.v, bop.v);
      }
      #pragma unroll
      for (int r = 0; r < 4; ++r)
        s_C[mf * 16 + g * 4 + r][nf * 16 + lo] = ac[r];
    }
  }

  // ---- hoist pairwise W fragments (iteration-invariant, from global) ----
  F8 bfr[4][4];   // [ks][nf], k = 128 + ks*32 + g*8, h-row = nf*16+lo
  #pragma unroll
  for (int ks = 0; ks < 4; ++ks)
    #pragma unroll
    for (int nf = 0; nf < 4; ++nf)
      bfr[ks][nf].v = *(const bf16x8*)&wtg[(nf * 16 + lo) * 256 + 128 + ks * 32 + g * 8];

  __syncthreads();

  // ---- main loop: wave owns i-rows wv*4 .. wv*4+3 ----
  for (int ii = 0; ii < 4; ++ii) {
    const int iL = wv * 4 + ii;

    f32x4 as4[4];
    #pragma unroll
    for (int nf = 0; nf < 4; ++nf)
      as4[nf] = *(const f32x4*)&s_A[iL][nf * 16 + g * 4];

    float oiv[16];
    {
      F8 u0, u1;
      u0.v = *(const bf16x8*)&s_oi[iL][g * 8];
      u1.v = *(const bf16x8*)&s_oi[iL][32 + g * 8];
      #pragma unroll
      for (int e = 0; e < 8; ++e) {
        oiv[e]     = (float)u0.h[e];
        oiv[8 + e] = (float)u1.h[e];
      }
    }

    #pragma unroll
    for (int jh = 0; jh < 2; ++jh) {
      // features for pair col lo: j = tj0 + jh*16 + lo
      F8 fb0, fb1, fb2, fb3;
      {
        F8 v0, v1;
        v0.v = *(const bf16x8*)&s_oj[jh * 16 + lo][g * 8];
        v1.v = *(const bf16x8*)&s_oj[jh * 16 + lo][32 + g * 8];
        #pragma unroll
        for (int e = 0; e < 8; ++e) {
          float p0 = (float)v0.h[e], p1 = (float)v1.h[e];
          float d0 = oiv[e] - p0,    d1 = oiv[8 + e] - p1;
          fb0.h[e] = (__bf16)fabsf(d0);
          fb1.h[e] = (__bf16)fabsf(d1);
          fb2.h[e] = (__bf16)(oiv[e] * p0);
          fb3.h[e] = (__bf16)(oiv[8 + e] * p1);
        }
      }

      f32x4 acc0, acc1, acc2, acc3;
      {
        f32x4 c0 = *(const f32x4*)&s_C[jh * 16 + lo][0 * 16 + g * 4];
        f32x4 c1 = *(const f32x4*)&s_C[jh * 16 + lo][1 * 16 + g * 4];
        f32x4 c2 = *(const f32x4*)&s_C[jh * 16 + lo][2 * 16 + g * 4];
        f32x4 c3 = *(const f32x4*)&s_C[jh * 16 + lo][3 * 16 + g * 4];
        acc0 = as4[0] + c0; acc1 = as4[1] + c1;
        acc2 = as4[2] + c2; acc3 = as4[3] + c3;
      }

      MFMA(acc0, bfr[0][0].v, fb0.v); MFMA(acc1, bfr[0][1].v, fb0.v);
      MFMA(acc2, bfr[0][2].v, fb0.v); MFMA(acc3, bfr[0][3].v, fb0.v);
      MFMA(acc0, bfr[1][0].v, fb1.v); MFMA(acc1, bfr[1][1].v, fb1.v);
      MFMA(acc2, bfr[1][2].v, fb1.v); MFMA(acc3, bfr[1][3].v, fb1.v);
      MFMA(acc0, bfr[2][0].v, fb2.v); MFMA(acc1, bfr[2][1].v, fb2.v);
      MFMA(acc2, bfr[2][2].v, fb2.v); MFMA(acc3, bfr[2][3].v, fb2.v);
      MFMA(acc0, bfr[3][0].v, fb3.v); MFMA(acc1, bfr[3][1].v, fb3.v);
      MFMA(acc2, bfr[3][2].v, fb3.v); MFMA(acc3, bfr[3][3].v, fb3.v);

      // epilogue: relu + W2 partial, reduce over g (2 shfl)
      float part = 0.f;
      {
        f32x4 w0 = *(const f32x4*)&s_w2[0 * 16 + g * 4];
        f32x4 w1 = *(const f32x4*)&s_w2[1 * 16 + g * 4];
        f32x4 w2q = *(const f32x4*)&s_w2[2 * 16 + g * 4];
        f32x4 w3 = *(const f32x4*)&s_w2[3 * 16 + g * 4];
        #pragma unroll
        for (int r = 0; r < 4; ++r) {
          part = fmaf(fmaxf(acc0[r], 0.f), w0[r], part);
          part = fmaf(fmaxf(acc1[r], 0.f), w1[r], part);
          part = fmaf(fmaxf(acc2[r], 0.f), w2q[r], part);
          part = fmaf(fmaxf(acc3[r], 0.f), w3[r], part);
        }
      }
      part += __shfl_xor(part, 16);
      part += __shfl_xor(part, 32);
      if (g == 0) s_q[iL][jh * 16 + lo] = part;
    }
  }
  __syncthreads();

  // ---- final: Q store + block top-2 candidates ----
  {
    const float b2v = b2[0];
    const int e0 = t * 2;
    const int row = e0 >> 5, col0 = e0 & 31;
    const int i = ti0 + row;
    float v1 = -INFINITY, v2 = -INFINITY;
    int   i1 = 0x7fffffff, i2 = 0x7fffffff;
    const int mbase = i * (Nn - 1) - (i * (i - 1)) / 2 - i - 1;
    #pragma unroll
    for (int e = 0; e < 2; ++e) {
      const int col = col0 + e;
      const int j = tj0 + col;
      const float qv = s_q[row][col] + b2v;
      if (j > i) {
        const int m = mbase + j;
        Q[(size_t)batch * Mm + m] = qv;
        top2_update(qv, m, v1, i1, v2, i2);
      }
    }
    #pragma unroll
    for (int s = 1; s < 64; s <<= 1) {
      float u1 = __shfl_xor(v1, s); int j1 = __shfl_xor(i1, s);
      float u2 = __shfl_xor(v2, s); int j2 = __shfl_xor(i2, s);
      top2_update(u1, j1, v1, i1, v2, i2);
      top2_update(u2, j2, v1, i1, v2, i2);
    }
    if (l == 0) {
      s_red[wv][0] = v1; s_red[wv][1] = __int_as_float(i1);
      s_red[wv][2] = v2; s_red[wv][3] = __int_as_float(i2);
    }
    __syncthreads();
    if (t == 0) {
      float a1 = s_red[0][0]; int x1 = __float_as_int(s_red[0][1]);
      float a2 = s_red[0][2]; int x2 = __float_as_int(s_red[0][3]);
      #pragma unroll
      for (int e = 1; e < 4; ++e) {
        top2_update(s_red[e][0], __float_as_int(s_red[e][1]), a1, x1, a2, x2);
        top2_update(s_red[e][2], __float_as_int(s_red[e][3]), a1, x1, a2, x2);
      }
      float* cp = cand + (size_t)blk * 4;
      cp[0] = a1; cp[1] = __int_as_float(x1);
      cp[2] = a2; cp[3] = __int_as_float(x2);
    }
  }
}

// ---------------------------------------------------------------------------
// Rank kernel: per batch, merge 144 candidates -> top-8 (by bf16 Q),
// recompute those 8 exactly in fp32, pick exact top-2 (jax tie rule).
// ---------------------------------------------------------------------------
__global__ __launch_bounds__(256) void rank_kernel(
    const float* __restrict__ O, const float* __restrict__ W1,
    const float* __restrict__ b1, const float* __restrict__ W2,
    const float* __restrict__ cand, int* __restrict__ ws2)
{
  const int b = blockIdx.x;
  const int t = threadIdx.x;
  __shared__ float s_cv[144];
  __shared__ int   s_ci[144];
  __shared__ int   s_m[8];
  __shared__ int   s_ij[8][2];
  __shared__ float s_or[8][2][64];
  __shared__ float s_part[8][32];
  __shared__ float s_qe[8];

  if (t < 144) {
    const float* cp = cand + (size_t)(b * 72 + (t >> 1)) * 4;
    s_cv[t] = cp[(t & 1) * 2];
    s_ci[t] = __float_as_int(cp[(t & 1) * 2 + 1]);
  }
  __syncthreads();
  if (t < 144) {
    float v = s_cv[t]; int m = s_ci[t];
    int rank = 0;
    for (int e = 0; e < 144; ++e) {
      float u = s_cv[e]; int n = s_ci[e];
      rank += (u > v || (u == v && n < m)) ? 1 : 0;
    }
    if (rank < 8) s_m[rank] = m;
  }
  __syncthreads();
  if (t < 16) {
    int m = s_m[t >> 1];
    int i = 0, rem = m;
    while (rem >= Nn - 1 - i) { rem -= Nn - 1 - i; ++i; }
    int j = i + 1 + rem;
    s_ij[t >> 1][t & 1] = (t & 1) ? j : i;
  }
  __syncthreads();
  {
    int c = t >> 5, rr = (t >> 4) & 1, c4 = (t & 15) * 4;
    int row = s_ij[c][rr];
    *(float4*)&s_or[c][rr][c4] = *(const float4*)&O[((size_t)b * Nn + row) * 64 + c4];
  }
  __syncthreads();
  {
    int c = t >> 5, hh = t & 31, h2 = hh * 2;
    float z0 = b1[h2], z1 = b1[h2 + 1];
    for (int d = 0; d < 64; ++d) {
      float oi = s_or[c][0][d], oj = s_or[c][1][d];
      float f3 = fabsf(oi - oj), f4 = oi * oj;
      float2 wa = *(const float2*)&W1[(d      ) * 64 + h2];
      float2 wb = *(const float2*)&W1[(64 + d ) * 64 + h2];
      float2 wc = *(const float2*)&W1[(128 + d) * 64 + h2];
      float2 wd = *(const float2*)&W1[(192 + d) * 64 + h2];
      z0 += oi * wa.x + oj * wb.x + f3 * wc.x + f4 * wd.x;
      z1 += oi * wa.y + oj * wb.y + f3 * wc.y + f4 * wd.y;
    }
    s_part[c][hh] = fmaxf(z0, 0.f) * W2[h2] + fmaxf(z1, 0.f) * W2[h2 + 1];
  }
  __syncthreads();
  if (t < 8) {
    float s = 0.f;
    for (int e = 0; e < 32; ++e) s += s_part[t][e];
    s_qe[t] = s;
  }
  __syncthreads();
  if (t == 0) {
    float v1 = -INFINITY, v2 = -INFINITY;
    int   i1 = 0x7fffffff, i2 = 0x7fffffff;
    for (int e = 0; e < 8; ++e)
      top2_update(s_qe[e], s_m[e], v1, i1, v2, i2);
    ws2[b * 2] = i1; ws2[b * 2 + 1] = i2;
  }
}

// ---------------------------------------------------------------------------
// Mask kernel
// ---------------------------------------------------------------------------
__global__ __launch_bounds__(256) void mask_kernel(
    const int* __restrict__ ws2, float* __restrict__ mask)
{
  const int b = blockIdx.x >> 3, cch = blockIdx.x & 7, t = threadIdx.x;
  const int k0 = ws2[b * 2], k1 = ws2[b * 2 + 1];
  float* mb = mask + (size_t)b * Mm;
  const int m0 = cch * CHUNK;
  for (int m = m0 + t; m < m0 + CHUNK; m += 256)
    mb[m] = (m == k0 || m == k1) ? 1.0f : 0.0f;
}

extern "C" void kernel_launch(void* const* d_in, const int* in_sizes, int n_in,
                              void* d_out, int out_size, void* d_ws, size_t ws_size,
                              hipStream_t stream) {
  const float* O  = (const float*)d_in[0];
  const float* W1 = (const float*)d_in[1];
  const float* b1 = (const float*)d_in[2];
  const float* W2 = (const float*)d_in[3];
  const float* b2 = (const float*)d_in[4];

  float* Q    = (float*)d_out;
  float* mask = Q + (size_t)Bn * Mm;

  unsigned short* wtg = (unsigned short*)d_ws;                    // 32768 B
  float* cand = (float*)((char*)d_ws + 32768);                    // 18432 B
  int*   ws2  = (int*)((char*)d_ws + 32768 + 18432);              // 128 B

  prep_w1t<<<dim3(64), dim3(256), 0, stream>>>(W1, wtg);
  pair_kernel<<<dim3(Bn * 72), dim3(256), 0, stream>>>(O, b1, W2, b2, wtg, Q, cand);
  rank_kernel<<<dim3(Bn), dim3(256), 0, stream>>>(O, W1, b1, W2, cand, ws2);
  mask_kernel<<<dim3(Bn * 8), dim3(256), 0, stream>>>(ws2, mask);
}